// Round 15
// baseline (194.378 us; speedup 1.0000x reference)
//
#include <hip/hip_runtime.h>

// MHA forward: out = softmax(mask(QK^T/8)) V, with QKV/out projections.
// B=4, S=2048, D=1024, H=16, hd=64. fp32 in/out, bf16 MFMA compute.
// Mask [B,1,1,S] -> compact K/V to unmasked keys (~50%). Softmax scale
// folded into K projection. V-GEMM and attn-PV use operand-swapped MFMA
// so transposed outputs store lane-contiguously (coalesced epilogues).

#define SEQ   2048
#define EDIM  1024
#define NHEAD 16
#define HDIM  64
#define NBAT  4
#define MTOK  8192           // B*S

typedef __attribute__((ext_vector_type(8))) __bf16 bf16x8;
typedef __attribute__((ext_vector_type(4))) __bf16 bf16x4;
typedef __attribute__((ext_vector_type(4))) float f32x4;
typedef __attribute__((ext_vector_type(16))) float f32x16;
typedef __attribute__((ext_vector_type(8))) unsigned short us8;
typedef __attribute__((ext_vector_type(4))) unsigned short us4;
typedef unsigned short u16;

// log2(e)/8 : folds the 1/sqrt(hd) scale and the exp->exp2 conversion
#define SCL   0.1803368801111244f

__device__ __forceinline__ u16 bfbits(float f) {
    __bf16 h = (__bf16)f;
    return __builtin_bit_cast(u16, h);
}
__device__ __forceinline__ bf16x8 bc(us8 v) { return __builtin_bit_cast(bf16x8, v); }
__device__ __forceinline__ float exp2fast(float x) {
    float r;
    asm("v_exp_f32 %0, %1" : "=v"(r) : "v"(x));
    return r;
}
// async global->LDS, 16B per lane; LDS dest = wave-uniform base + lane*16
__device__ __forceinline__ void glds16(const void* g, void* l) {
    __builtin_amdgcn_global_load_lds(
        (const __attribute__((address_space(1))) unsigned int*)g,
        (__attribute__((address_space(3))) unsigned int*)l, 16, 0, 0);
}

// ---------------------------------------------------------------------------
// Kernel 0: per-batch compaction of the key mask.
// ---------------------------------------------------------------------------
__global__ __launch_bounds__(256) void prep_kernel(const int* __restrict__ mask,
                                                   int* __restrict__ idxl,
                                                   int* __restrict__ cntp) {
    __shared__ int psum[257];
    const int b = blockIdx.x, t = threadIdx.x;
    const int* mp = mask + b * SEQ;
    int m8[8]; int s = 0;
#pragma unroll
    for (int i = 0; i < 8; ++i) { m8[i] = mp[t * 8 + i]; s += (m8[i] != 0); }
    psum[t + 1] = s;
    __syncthreads();
    if (t == 0) { psum[0] = 0; for (int i = 1; i <= 256; ++i) psum[i] += psum[i - 1]; }
    __syncthreads();
    int ex = psum[t];
#pragma unroll
    for (int i = 0; i < 8; ++i)
        if (m8[i] != 0) idxl[b * SEQ + (ex++)] = t * 8 + i;
    if (t == 0) cntp[b] = psum[256];
}

// ---------------------------------------------------------------------------
// Kernel 1: 4x W [K,N] fp32 -> WT [N,K] bf16 (transpose + cast)
// ---------------------------------------------------------------------------
__global__ __launch_bounds__(256) void wtrans4_kernel(const float* __restrict__ W0,
                                                      const float* __restrict__ W1,
                                                      const float* __restrict__ W2,
                                                      const float* __restrict__ W3,
                                                      u16* __restrict__ WT) {
    __shared__ float tile[32][33];
    const int tx = threadIdx.x, ty = threadIdx.y;
    const int bx = blockIdx.x,  by = blockIdx.y, wz = blockIdx.z;
    const float* W = (wz == 0) ? W0 : (wz == 1) ? W1 : (wz == 2) ? W2 : W3;
    u16* O = WT + (size_t)wz * EDIM * EDIM;
#pragma unroll
    for (int i = 0; i < 4; ++i)
        tile[ty + i * 8][tx] = W[(size_t)(by * 32 + ty + i * 8) * EDIM + bx * 32 + tx];
    __syncthreads();
#pragma unroll
    for (int i = 0; i < 4; ++i) {
        int n = bx * 32 + ty + i * 8;
        int k = by * 32 + tx;
        O[(size_t)n * EDIM + k] = bfbits(tile[tx][ty + i * 8]);
    }
}

// ---------------------------------------------------------------------------
// Kernel 1b: fused fp32->bf16 convert (+gather for K/V), coalesced.
// One WAVE per row; each load instruction is lane-contiguous (16B/lane).
// ---------------------------------------------------------------------------
__global__ __launch_bounds__(256) void cvtg_kernel(const float* __restrict__ q,
                                                   const float* __restrict__ k,
                                                   const float* __restrict__ v,
                                                   const int* __restrict__ idxl,
                                                   const int* __restrict__ cntp,
                                                   u16* __restrict__ oq,
                                                   u16* __restrict__ ok,
                                                   u16* __restrict__ ov) {
    const int w = threadIdx.x >> 6, lane = threadIdx.x & 63;
    for (int rid = blockIdx.x * 4 + w; rid < 3 * MTOK; rid += 8192) {
        const int sel  = rid >> 13;          // 0,1,2 (8192 rows each)
        const int grow = rid & 8191;
        const float* src = nullptr;
        u16* dst;
        bool zero = false;
        if (sel == 0) {
            src = q + (size_t)grow * EDIM;
            dst = oq + (size_t)grow * EDIM;
        } else {
            const int b = grow >> 11, j = grow & 2047;
            const int cn = cntp[b];
            dst = (sel == 1 ? ok : ov) + (size_t)grow * EDIM;
            if (j < cn) {
                src = (sel == 1 ? k : v) + (size_t)(b * SEQ + idxl[b * SEQ + j]) * EDIM;
            } else if (j < ((cn + 127) & ~127)) {
                zero = true;
            } else {
                continue;
            }
        }
        if (zero) {
            us4 z = {0, 0, 0, 0};
#pragma unroll
            for (int it = 0; it < 4; ++it)
                *(us4*)(dst + it * 256 + lane * 4) = z;
            continue;
        }
#pragma unroll
        for (int it = 0; it < 4; ++it) {
            f32x4 vv = *(const f32x4*)(src + it * 256 + lane * 4);
            us4 r;
#pragma unroll
            for (int j2 = 0; j2 < 4; ++j2) r[j2] = bfbits(vv[j2]);
            *(us4*)(dst + it * 256 + lane * 4) = r;
        }
    }
}

// ---------------------------------------------------------------------------
// Kernel 2a: merged QKV projections, one 1536-block launch.
//   which = id>>9: 0=Q -> [B,H,S,64]; 1=K (scaled) -> [B,H,S,64];
//                  2=V -> [B,H,64,S] via OPERAND-SWAPPED MFMA (coalesced).
// A: pre-converted (pre-gathered) bf16; 2-buffer glds, 32KB LDS.
// ---------------------------------------------------------------------------
__global__ __launch_bounds__(256) void qkv_gemm_kernel(
        const u16* __restrict__ Aq, const u16* __restrict__ Ak,
        const u16* __restrict__ Av, const u16* __restrict__ WTall,
        const float* __restrict__ bqp, const float* __restrict__ bkp,
        const float* __restrict__ bvp,
        u16* __restrict__ Qb, u16* __restrict__ Kb, u16* __restrict__ Vb,
        const int* __restrict__ cntp) {
    const int id    = blockIdx.x;
    const int which = id >> 9;            // 0,1,2
    const int sub   = id & 511;
    const int r_    = sub >> 3;
    const int grp   = r_ >> 5, bnq = (r_ >> 2) & 7, bmin = r_ & 3;
    const int bm    = (sub & 7) + 8 * (grp * 4 + bmin);
    const int bn    = bnq;

    const u16*   A    = (which == 0) ? Aq : (which == 1) ? Ak : Av;
    const u16*   WT   = WTall + (size_t)which * EDIM * EDIM;
    const float* bias = (which == 0) ? bqp : (which == 1) ? bkp : bvp;
    u16*         outp = (which == 0) ? Qb : (which == 1) ? Kb : Vb;
    const float  oscale = (which == 1) ? SCL : 1.0f;

    int cn = SEQ;
    if (which > 0) {
        cn = cntp[bm >> 4];
        if (((bm & 15) * 128) >= cn) return;   // fully-padded block
    }

    __shared__ __align__(16) u16 As[2][128][32];
    __shared__ __align__(16) u16 Bs[2][128][32];

    const int tid  = threadIdx.x;
    const int lane = tid & 63, w = tid >> 6;
    const int g    = lane >> 4, l15 = lane & 15;
    const int wrow = w >> 1, wcol = w & 1;

    const char* pa[2]; const char* pb[2];
#pragma unroll
    for (int t = 0; t < 2; ++t) {
        const int rloc = w * 32 + t * 16 + (lane >> 2);
        const int scol = ((lane & 3) ^ ((lane >> 3) & 3)) * 8;
        pa[t] = (const char*)(A + (size_t)(bm * 128 + rloc) * EDIM + scol);
        pb[t] = (const char*)(WT + (size_t)(bn * 128 + rloc) * EDIM + scol);
    }

    auto STAGE = [&](int bufn, int ko) {
        char* abase = (char*)&As[bufn][0][0] + w * 2048;
        char* bbase = (char*)&Bs[bufn][0][0] + w * 2048;
#pragma unroll
        for (int t = 0; t < 2; ++t) {
            glds16(pa[t] + (size_t)ko * 2, abase + t * 1024);
            glds16(pb[t] + (size_t)ko * 2, bbase + t * 1024);
        }
    };

    f32x4 acc[4][4] = {};
    constexpr int NT = EDIM / 32;

    STAGE(0, 0);
    __syncthreads();

    int buf = 0;
#pragma unroll 1
    for (int kt = 0; kt < NT; ++kt) {
        if (kt < NT - 1) STAGE(buf ^ 1, (kt + 1) * 32);

        bf16x8 af[4], bfr[4];
        const int x = (l15 >> 1) & 3;
#pragma unroll
        for (int i = 0; i < 4; ++i) {
            const int rowA = wrow * 64 + i * 16 + l15;
            af[i] = bc(*(const us8*)((const u16*)&As[buf][0][0] + rowA * 32 + ((g ^ x) * 8)));
            const int rowB = wcol * 64 + i * 16 + l15;
            bfr[i] = bc(*(const us8*)((const u16*)&Bs[buf][0][0] + rowB * 32 + ((g ^ x) * 8)));
        }

        if (which == 2) {
            // swapped operands: C rows <- W-side (n), cols <- A-side (m)
#pragma unroll
            for (int i = 0; i < 4; ++i)
#pragma unroll
                for (int j = 0; j < 4; ++j)
                    acc[i][j] = __builtin_amdgcn_mfma_f32_16x16x32_bf16(bfr[j], af[i], acc[i][j], 0, 0, 0);
        } else {
#pragma unroll
            for (int i = 0; i < 4; ++i)
#pragma unroll
                for (int j = 0; j < 4; ++j)
                    acc[i][j] = __builtin_amdgcn_mfma_f32_16x16x32_bf16(af[i], bfr[j], acc[i][j], 0, 0, 0);
        }

        __syncthreads();
        buf ^= 1;
    }

    if (which == 2) {
        // V epilogue (swapped): n = bn*128 + wcol*64 + j*16 + g*4 + r (row),
        // m = bm*128 + wrow*64 + i*16 + l15 (col) -> stores contiguous in s.
#pragma unroll
        for (int i = 0; i < 4; ++i) {
            const int mglob = bm * 128 + wrow * 64 + i * 16 + l15;
            const int bb = mglob >> 11, s = mglob & 2047;
            const bool dead = (s >= cn);
#pragma unroll
            for (int j = 0; j < 4; ++j) {
#pragma unroll
                for (int r = 0; r < 4; ++r) {
                    const int gn = bn * 128 + wcol * 64 + j * 16 + g * 4 + r;
                    float val = acc[i][j][r] + bias[gn];
                    if (dead) val = 0.f;
                    const int hh = gn >> 6, d = gn & 63;
                    outp[((size_t)(bb * NHEAD + hh) << 17) + (size_t)d * SEQ + s] = bfbits(val);
                }
            }
        }
    } else {
        // Q/K epilogue: col = lane&15 (d-contiguous), row = g*4 + r
#pragma unroll
        for (int i = 0; i < 4; ++i) {
#pragma unroll
            for (int j = 0; j < 4; ++j) {
                const int gm0 = bm * 128 + wrow * 64 + i * 16 + g * 4;
                const int gn  = bn * 128 + wcol * 64 + j * 16 + l15;
                const float bv = bias[gn];
#pragma unroll
                for (int r = 0; r < 4; ++r) {
                    float val = (acc[i][j][r] + bv) * oscale;
                    const int m = gm0 + r;
                    if (which > 0 && (m & 2047) >= cn) val = 0.f;
                    const int b = m >> 11, s = m & 2047;
                    const int h = gn >> 6, d = gn & 63;
                    outp[((size_t)(b * NHEAD + h) << 17) + s * HDIM + d] = bfbits(val);
                }
            }
        }
    }
}

// ---------------------------------------------------------------------------
// Kernel 2b: O-projection. C[M,N] fp32 = Abuf(bf16)[M,1024] * Wo + bo.
// ---------------------------------------------------------------------------
__global__ __launch_bounds__(256) void o_gemm_kernel(const u16* __restrict__ Ap,
                                                     const u16* __restrict__ WT,
                                                     const float* __restrict__ bias,
                                                     float* __restrict__ outp) {
    const int id  = blockIdx.x;
    const int r_  = id >> 3;
    const int grp = r_ >> 5, bnq = (r_ >> 2) & 7, bmin = r_ & 3;
    const int bm  = (id & 7) + 8 * (grp * 4 + bmin);
    const int bn  = bnq;

    __shared__ __align__(16) u16 As[2][128][32];
    __shared__ __align__(16) u16 Bs[2][128][32];

    const int tid  = threadIdx.x;
    const int lane = tid & 63, w = tid >> 6;
    const int g    = lane >> 4, l15 = lane & 15;
    const int wrow = w >> 1, wcol = w & 1;

    const char* pa[2]; const char* pb[2];
#pragma unroll
    for (int t = 0; t < 2; ++t) {
        const int rloc = w * 32 + t * 16 + (lane >> 2);
        const int scol = ((lane & 3) ^ ((lane >> 3) & 3)) * 8;
        pa[t] = (const char*)(Ap + (size_t)(bm * 128 + rloc) * EDIM + scol);
        pb[t] = (const char*)(WT + (size_t)(bn * 128 + rloc) * EDIM + scol);
    }

    auto STAGE = [&](int bufn, int ko) {
        char* abase = (char*)&As[bufn][0][0] + w * 2048;
        char* bbase = (char*)&Bs[bufn][0][0] + w * 2048;
#pragma unroll
        for (int t = 0; t < 2; ++t) {
            glds16(pa[t] + (size_t)ko * 2, abase + t * 1024);
            glds16(pb[t] + (size_t)ko * 2, bbase + t * 1024);
        }
    };

    f32x4 acc[4][4] = {};
    constexpr int NT = EDIM / 32;

    STAGE(0, 0);
    __syncthreads();

    int buf = 0;
#pragma unroll 1
    for (int kt = 0; kt < NT; ++kt) {
        if (kt < NT - 1) STAGE(buf ^ 1, (kt + 1) * 32);

        bf16x8 af[4], bfr[4];
        const int x = (l15 >> 1) & 3;
#pragma unroll
        for (int i = 0; i < 4; ++i) {
            const int rowA = wrow * 64 + i * 16 + l15;
            af[i] = bc(*(const us8*)((const u16*)&As[buf][0][0] + rowA * 32 + ((g ^ x) * 8)));
            const int rowB = wcol * 64 + i * 16 + l15;
            bfr[i] = bc(*(const us8*)((const u16*)&Bs[buf][0][0] + rowB * 32 + ((g ^ x) * 8)));
        }

#pragma unroll
        for (int i = 0; i < 4; ++i)
#pragma unroll
            for (int j = 0; j < 4; ++j)
                acc[i][j] = __builtin_amdgcn_mfma_f32_16x16x32_bf16(af[i], bfr[j], acc[i][j], 0, 0, 0);

        __syncthreads();
        buf ^= 1;
    }

#pragma unroll
    for (int i = 0; i < 4; ++i) {
#pragma unroll
        for (int j = 0; j < 4; ++j) {
            const int gm0 = bm * 128 + wrow * 64 + i * 16 + g * 4;
            const int gn  = bn * 128 + wcol * 64 + j * 16 + l15;
            const float bv = bias[gn];
#pragma unroll
            for (int r = 0; r < 4; ++r)
                outp[(size_t)(gm0 + r) * EDIM + gn] = acc[i][j][r] + bv;
        }
    }
}

// ---------------------------------------------------------------------------
// Kernel 3: flash attention over COMPACTED keys, 32x32 MFMA, in-register P.
// PV and rowsum use P as the A-operand (operand swap) so the output C has
// cols = d = l31 -> O-stores are 64B-contiguous per instruction, and the
// rowsum rows align with ot rows (lane-local normalization, 16 rcp).
// ---------------------------------------------------------------------------
__global__ __launch_bounds__(256) void attn_kernel(const u16* __restrict__ Q,
                                                   const u16* __restrict__ K,
                                                   const u16* __restrict__ VT,
                                                   const int* __restrict__ cntp,
                                                   u16* __restrict__ O) {
    __shared__ u16 Klds[2][64][64];
    __shared__ u16 Vlds[2][64][64];

    const int tid = threadIdx.x, lane = tid & 63, w = tid >> 6;
    const int h = lane >> 5, l31 = lane & 31;

    const int id  = blockIdx.x;             // 0..1023, XCD-aware mapping
    const int bh  = (id & 7) * 8 + ((id >> 3) >> 4);
    const int qb  = (id >> 3) & 15;
    const int b   = bh >> 4, hd_ = bh & 15;

    const u16* Qp = Q + ((size_t)bh << 17);
    const u16* Kp = K + ((size_t)bh << 17);
    const u16* Vp = VT + ((size_t)bh << 17);
    const int q0w = qb * 128 + w * 32;

    const int cn  = cntp[b];
    const int ktc = (cn + 63) >> 6;

    bf16x8 qf[4];
#pragma unroll
    for (int khd = 0; khd < 4; ++khd)
        qf[khd] = bc(*(const us8*)&Qp[(size_t)(q0w + l31) * HDIM + khd * 16 + h * 8]);

    const int b_  = l31 & 3, hp = (l31 >> 2) & 1, cc = l31 >> 3;
    const int piR = 16 * (cc & 1) + 8 * hp + 4 * (cc >> 1) + b_;
    const int swk = b_ | (hp << 2);
    const int swv = l31 & 7;

    const int lr = lane >> 3, lg = lane & 7;
    const u16* pKs[2]; const u16* pVs[2];
#pragma unroll
    for (int t = 0; t < 2; ++t) {
        const int rloc = w * 16 + t * 8 + lr;
        const int xk = (rloc & 3) | (((rloc >> 3) & 1) << 2);
        pKs[t] = Kp + (size_t)rloc * HDIM + ((lg ^ xk) << 3);
        const int xv = rloc & 7;
        pVs[t] = Vp + (size_t)rloc * SEQ + ((lg ^ xv) << 3);
    }

    auto STAGE = [&](int bufn, int kb) {
#pragma unroll
        for (int t = 0; t < 2; ++t) {
            glds16(pKs[t] + (size_t)kb * HDIM, &Klds[bufn][w * 16 + t * 8][0]);
            glds16(pVs[t] + kb,                &Vlds[bufn][w * 16 + t * 8][0]);
        }
    };

    f32x16 ot[2] = {};
    f32x16 ls = {};

    bf16x8 onesf;
#pragma unroll
    for (int j = 0; j < 8; ++j) onesf[j] = (__bf16)1.0f;

    STAGE(0, 0);
    __syncthreads();

    for (int kt = 0; kt < ktc; ++kt) {
        const int cur = kt & 1;
        const bool more = (kt + 1) < ktc;
        if (more) STAGE(cur ^ 1, (kt + 1) * 64);

        f32x16 st[2] = {};
        __builtin_amdgcn_s_setprio(1);
#pragma unroll
        for (int kb2 = 0; kb2 < 2; ++kb2) {
            const u16* Kr = &Klds[cur][kb2 * 32 + piR][0];
#pragma unroll
            for (int khd = 0; khd < 4; ++khd) {
                bf16x8 kf = bc(*(const us8*)&Kr[(khd * 16 + h * 8) ^ (swk << 3)]);
                st[kb2] = __builtin_amdgcn_mfma_f32_32x32x16_bf16(kf, qf[khd], st[kb2], 0, 0, 0);
            }
        }
        __builtin_amdgcn_s_setprio(0);

#pragma unroll
        for (int kb2 = 0; kb2 < 2; ++kb2)
#pragma unroll
            for (int e = 0; e < 16; ++e)
                st[kb2][e] = exp2fast(st[kb2][e]);

        if (kt == ktc - 1) {
            const int kbase = kt * 64;
#pragma unroll
            for (int kb2 = 0; kb2 < 2; ++kb2)
#pragma unroll
                for (int cp = 0; cp < 4; ++cp)
#pragma unroll
                    for (int j = 0; j < 4; ++j) {
                        const int key = kbase + kb2 * 32 + 16 * (cp & 1) + 4 * (cp >> 1) + 8 * h + j;
                        if (key >= cn) st[kb2][cp * 4 + j] = 0.f;
                    }
        }

        bf16x8 pf[4];
#pragma unroll
        for (int s = 0; s < 4; ++s) {
            const int kb2 = s >> 1, sel = (s & 1) * 4;
#pragma unroll
            for (int j = 0; j < 4; ++j) {
                pf[s][j]     = (__bf16)st[kb2][sel + j];
                pf[s][4 + j] = (__bf16)st[kb2][8 + sel + j];
            }
        }

        __builtin_amdgcn_s_setprio(1);
        // rowsum (swapped): ls rows = q = crow(e,h), all cols identical
#pragma unroll
        for (int s = 0; s < 4; ++s)
            ls = __builtin_amdgcn_mfma_f32_32x32x16_bf16(pf[s], onesf, ls, 0, 0, 0);
        // PV (swapped): A = P (rows q), B = V^T (cols d = l31)
#pragma unroll
        for (int dblk = 0; dblk < 2; ++dblk) {
            const u16* Vr = &Vlds[cur][dblk * 32 + l31][0];
#pragma unroll
            for (int s = 0; s < 4; ++s) {
                bf16x8 vf = bc(*(const us8*)&Vr[(s * 16 + h * 8) ^ (swv << 3)]);
                ot[dblk] = __builtin_amdgcn_mfma_f32_32x32x16_bf16(pf[s], vf, ot[dblk], 0, 0, 0);
            }
        }
        __builtin_amdgcn_s_setprio(0);

        __syncthreads();
    }

    // store: element e -> q = (e&3)+8*(e>>2)+4h, d = dblk*32 + l31
    // (64B-contiguous per instruction across the 32 lanes)
    const size_t rowbase = (size_t)b * SEQ + qb * 128 + w * 32;
#pragma unroll
    for (int e = 0; e < 16; ++e) {
        const int qrow = (e & 3) + 8 * (e >> 2) + 4 * h;
        const float iv = 1.f / ls[e];
        const size_t off = (rowbase + qrow) * EDIM + hd_ * HDIM;
        O[off + l31]      = bfbits(ot[0][e] * iv);
        O[off + 32 + l31] = bfbits(ot[1][e] * iv);
    }
}

// ---------------------------------------------------------------------------
extern "C" void kernel_launch(void* const* d_in, const int* in_sizes, int n_in,
                              void* d_out, int out_size, void* d_ws, size_t ws_size,
                              hipStream_t stream) {
    const float* query = (const float*)d_in[0];
    const float* key   = (const float*)d_in[1];
    const float* value = (const float*)d_in[2];
    const int*   mask  = (const int*)d_in[3];
    const float* Wq = (const float*)d_in[4];  const float* bq = (const float*)d_in[5];
    const float* Wk = (const float*)d_in[6];  const float* bk = (const float*)d_in[7];
    const float* Wv = (const float*)d_in[8];  const float* bv = (const float*)d_in[9];
    const float* Wo = (const float*)d_in[10]; const float* bo = (const float*)d_in[11];

    char* ws = (char*)d_ws;
    const size_t WT_BYTES  = (size_t)EDIM * EDIM * 2;      // 2 MiB
    const size_t BUF_BYTES = (size_t)MTOK * EDIM * 2;      // 16 MiB
    u16* wtq   = (u16*)(ws);                               // q,k,v,o contiguous
    u16* wto   = (u16*)(ws + 3 * WT_BYTES);
    u16* Qbuf  = (u16*)(ws + 4 * WT_BYTES);
    u16* Kbuf  = (u16*)(ws + 4 * WT_BYTES + BUF_BYTES);
    u16* VTbuf = (u16*)(ws + 4 * WT_BYTES + 2 * BUF_BYTES);
    char* X    = ws + 4 * WT_BYTES + 3 * BUF_BYTES;
    u16* Qbf   = (u16*)X;
    u16* Kc    = (u16*)(X + BUF_BYTES);
    u16* Vc    = (u16*)(X + 2 * BUF_BYTES);
    u16* Abuf  = (u16*)X;          // overlays Qbf after qkv consumes it
    int* idxl  = (int*)(X + 3 * BUF_BYTES);
    int* cntp  = (int*)(X + 3 * BUF_BYTES + (size_t)MTOK * 4);

    prep_kernel<<<NBAT, 256, 0, stream>>>(mask, idxl, cntp);

    dim3 tgrid(32, 32, 4), tblk(32, 8);
    wtrans4_kernel<<<tgrid, tblk, 0, stream>>>(Wq, Wk, Wv, Wo, wtq);

    cvtg_kernel<<<2048, 256, 0, stream>>>(query, key, value,
                                          idxl, cntp, Qbf, Kc, Vc);

    qkv_gemm_kernel<<<1536, 256, 0, stream>>>(Qbf, Kc, Vc, wtq,
                                              bq, bk, bv, Qbuf, Kbuf, VTbuf,
                                              cntp);

    attn_kernel<<<1024, 256, 0, stream>>>(Qbuf, Kbuf, VTbuf, cntp, Abuf);

    o_gemm_kernel<<<512, 256, 0, stream>>>(Abuf, wto, bo, (float*)d_out);
}

// Round 16
// 186.391 us; speedup vs baseline: 1.0428x; 1.0428x over previous
//
#include <hip/hip_runtime.h>

// MHA forward: out = softmax(mask(QK^T/8)) V, with QKV/out projections.
// B=4, S=2048, D=1024, H=16, hd=64. fp32 in/out, bf16 MFMA compute.
// Mask [B,1,1,S] -> compact K/V to unmasked keys (~50%). Softmax scale
// folded into K projection. V projection is a SEPARATE kernel with
// operand-swapped MFMA (coalesced transposed stores) so Q/K codegen
// keeps its low register pressure.

#define SEQ   2048
#define EDIM  1024
#define NHEAD 16
#define HDIM  64
#define NBAT  4
#define MTOK  8192           // B*S

typedef __attribute__((ext_vector_type(8))) __bf16 bf16x8;
typedef __attribute__((ext_vector_type(4))) __bf16 bf16x4;
typedef __attribute__((ext_vector_type(4))) float f32x4;
typedef __attribute__((ext_vector_type(16))) float f32x16;
typedef __attribute__((ext_vector_type(8))) unsigned short us8;
typedef __attribute__((ext_vector_type(4))) unsigned short us4;
typedef unsigned short u16;

// log2(e)/8 : folds the 1/sqrt(hd) scale and the exp->exp2 conversion
#define SCL   0.1803368801111244f

__device__ __forceinline__ u16 bfbits(float f) {
    __bf16 h = (__bf16)f;
    return __builtin_bit_cast(u16, h);
}
__device__ __forceinline__ bf16x8 bc(us8 v) { return __builtin_bit_cast(bf16x8, v); }
__device__ __forceinline__ float exp2fast(float x) {
    float r;
    asm("v_exp_f32 %0, %1" : "=v"(r) : "v"(x));
    return r;
}
// async global->LDS, 16B per lane; LDS dest = wave-uniform base + lane*16
__device__ __forceinline__ void glds16(const void* g, void* l) {
    __builtin_amdgcn_global_load_lds(
        (const __attribute__((address_space(1))) unsigned int*)g,
        (__attribute__((address_space(3))) unsigned int*)l, 16, 0, 0);
}

// ---------------------------------------------------------------------------
// Kernel 0: per-batch compaction of the key mask.
// ---------------------------------------------------------------------------
__global__ __launch_bounds__(256) void prep_kernel(const int* __restrict__ mask,
                                                   int* __restrict__ idxl,
                                                   int* __restrict__ cntp) {
    __shared__ int psum[257];
    const int b = blockIdx.x, t = threadIdx.x;
    const int* mp = mask + b * SEQ;
    int m8[8]; int s = 0;
#pragma unroll
    for (int i = 0; i < 8; ++i) { m8[i] = mp[t * 8 + i]; s += (m8[i] != 0); }
    psum[t + 1] = s;
    __syncthreads();
    if (t == 0) { psum[0] = 0; for (int i = 1; i <= 256; ++i) psum[i] += psum[i - 1]; }
    __syncthreads();
    int ex = psum[t];
#pragma unroll
    for (int i = 0; i < 8; ++i)
        if (m8[i] != 0) idxl[b * SEQ + (ex++)] = t * 8 + i;
    if (t == 0) cntp[b] = psum[256];
}

// ---------------------------------------------------------------------------
// Kernel 1: 4x W [K,N] fp32 -> WT [N,K] bf16 (transpose + cast)
// ---------------------------------------------------------------------------
__global__ __launch_bounds__(256) void wtrans4_kernel(const float* __restrict__ W0,
                                                      const float* __restrict__ W1,
                                                      const float* __restrict__ W2,
                                                      const float* __restrict__ W3,
                                                      u16* __restrict__ WT) {
    __shared__ float tile[32][33];
    const int tx = threadIdx.x, ty = threadIdx.y;
    const int bx = blockIdx.x,  by = blockIdx.y, wz = blockIdx.z;
    const float* W = (wz == 0) ? W0 : (wz == 1) ? W1 : (wz == 2) ? W2 : W3;
    u16* O = WT + (size_t)wz * EDIM * EDIM;
#pragma unroll
    for (int i = 0; i < 4; ++i)
        tile[ty + i * 8][tx] = W[(size_t)(by * 32 + ty + i * 8) * EDIM + bx * 32 + tx];
    __syncthreads();
#pragma unroll
    for (int i = 0; i < 4; ++i) {
        int n = bx * 32 + ty + i * 8;
        int k = by * 32 + tx;
        O[(size_t)n * EDIM + k] = bfbits(tile[tx][ty + i * 8]);
    }
}

// ---------------------------------------------------------------------------
// Kernel 1b: fused fp32->bf16 convert (+gather for K/V), coalesced.
// ---------------------------------------------------------------------------
__global__ __launch_bounds__(256) void cvtg_kernel(const float* __restrict__ q,
                                                   const float* __restrict__ k,
                                                   const float* __restrict__ v,
                                                   const int* __restrict__ idxl,
                                                   const int* __restrict__ cntp,
                                                   u16* __restrict__ oq,
                                                   u16* __restrict__ ok,
                                                   u16* __restrict__ ov) {
    const int w = threadIdx.x >> 6, lane = threadIdx.x & 63;
    for (int rid = blockIdx.x * 4 + w; rid < 3 * MTOK; rid += 8192) {
        const int sel  = rid >> 13;          // 0,1,2 (8192 rows each)
        const int grow = rid & 8191;
        const float* src = nullptr;
        u16* dst;
        bool zero = false;
        if (sel == 0) {
            src = q + (size_t)grow * EDIM;
            dst = oq + (size_t)grow * EDIM;
        } else {
            const int b = grow >> 11, j = grow & 2047;
            const int cn = cntp[b];
            dst = (sel == 1 ? ok : ov) + (size_t)grow * EDIM;
            if (j < cn) {
                src = (sel == 1 ? k : v) + (size_t)(b * SEQ + idxl[b * SEQ + j]) * EDIM;
            } else if (j < ((cn + 127) & ~127)) {
                zero = true;
            } else {
                continue;
            }
        }
        if (zero) {
            us4 z = {0, 0, 0, 0};
#pragma unroll
            for (int it = 0; it < 4; ++it)
                *(us4*)(dst + it * 256 + lane * 4) = z;
            continue;
        }
#pragma unroll
        for (int it = 0; it < 4; ++it) {
            f32x4 vv = *(const f32x4*)(src + it * 256 + lane * 4);
            us4 r;
#pragma unroll
            for (int j2 = 0; j2 < 4; ++j2) r[j2] = bfbits(vv[j2]);
            *(us4*)(dst + it * 256 + lane * 4) = r;
        }
    }
}

// ---------------------------------------------------------------------------
// Kernel 2a: Q and K projections, one 1024-block launch.
//   which = id>>9: 0=Q (no gather), 1=K (gathered A, scaled). Both store
//   bf16 [B,H,S,64]. Unswapped MFMA only -> low VGPR.
// ---------------------------------------------------------------------------
__global__ __launch_bounds__(256) void qk_gemm_kernel(
        const u16* __restrict__ Aq, const u16* __restrict__ Ak,
        const u16* __restrict__ WTall,
        const float* __restrict__ bqp, const float* __restrict__ bkp,
        u16* __restrict__ Qb, u16* __restrict__ Kb,
        const int* __restrict__ cntp) {
    const int id    = blockIdx.x;
    const int which = id >> 9;            // 0,1
    const int sub   = id & 511;
    const int r_    = sub >> 3;
    const int grp   = r_ >> 5, bnq = (r_ >> 2) & 7, bmin = r_ & 3;
    const int bm    = (sub & 7) + 8 * (grp * 4 + bmin);
    const int bn    = bnq;

    const u16*   A    = (which == 0) ? Aq : Ak;
    const u16*   WT   = WTall + (size_t)which * EDIM * EDIM;
    const float* bias = (which == 0) ? bqp : bkp;
    u16*         outp = (which == 0) ? Qb : Kb;
    const float  oscale = (which == 1) ? SCL : 1.0f;

    int cn = SEQ;
    if (which == 1) {
        cn = cntp[bm >> 4];
        if (((bm & 15) * 128) >= cn) return;
    }

    __shared__ __align__(16) u16 As[2][128][32];
    __shared__ __align__(16) u16 Bs[2][128][32];

    const int tid  = threadIdx.x;
    const int lane = tid & 63, w = tid >> 6;
    const int g    = lane >> 4, l15 = lane & 15;
    const int wrow = w >> 1, wcol = w & 1;

    const char* pa[2]; const char* pb[2];
#pragma unroll
    for (int t = 0; t < 2; ++t) {
        const int rloc = w * 32 + t * 16 + (lane >> 2);
        const int scol = ((lane & 3) ^ ((lane >> 3) & 3)) * 8;
        pa[t] = (const char*)(A + (size_t)(bm * 128 + rloc) * EDIM + scol);
        pb[t] = (const char*)(WT + (size_t)(bn * 128 + rloc) * EDIM + scol);
    }

    auto STAGE = [&](int bufn, int ko) {
        char* abase = (char*)&As[bufn][0][0] + w * 2048;
        char* bbase = (char*)&Bs[bufn][0][0] + w * 2048;
#pragma unroll
        for (int t = 0; t < 2; ++t) {
            glds16(pa[t] + (size_t)ko * 2, abase + t * 1024);
            glds16(pb[t] + (size_t)ko * 2, bbase + t * 1024);
        }
    };

    f32x4 acc[4][4] = {};
    constexpr int NT = EDIM / 32;

    STAGE(0, 0);
    __syncthreads();

    int buf = 0;
#pragma unroll 1
    for (int kt = 0; kt < NT; ++kt) {
        if (kt < NT - 1) STAGE(buf ^ 1, (kt + 1) * 32);

        bf16x8 af[4], bfr[4];
        const int x = (l15 >> 1) & 3;
#pragma unroll
        for (int i = 0; i < 4; ++i) {
            const int rowA = wrow * 64 + i * 16 + l15;
            af[i] = bc(*(const us8*)((const u16*)&As[buf][0][0] + rowA * 32 + ((g ^ x) * 8)));
            const int rowB = wcol * 64 + i * 16 + l15;
            bfr[i] = bc(*(const us8*)((const u16*)&Bs[buf][0][0] + rowB * 32 + ((g ^ x) * 8)));
        }

#pragma unroll
        for (int i = 0; i < 4; ++i)
#pragma unroll
            for (int j = 0; j < 4; ++j)
                acc[i][j] = __builtin_amdgcn_mfma_f32_16x16x32_bf16(af[i], bfr[j], acc[i][j], 0, 0, 0);

        __syncthreads();
        buf ^= 1;
    }

    // epilogue: col = lane&15 (d-contiguous), row = g*4 + r
#pragma unroll
    for (int i = 0; i < 4; ++i) {
#pragma unroll
        for (int j = 0; j < 4; ++j) {
            const int gm0 = bm * 128 + wrow * 64 + i * 16 + g * 4;
            const int gn  = bn * 128 + wcol * 64 + j * 16 + l15;
            const float bv = bias[gn];
#pragma unroll
            for (int r = 0; r < 4; ++r) {
                float val = (acc[i][j][r] + bv) * oscale;
                const int m = gm0 + r;
                if (which == 1 && (m & 2047) >= cn) val = 0.f;
                const int b = m >> 11, s = m & 2047;
                const int h = gn >> 6, d = gn & 63;
                outp[((size_t)(b * NHEAD + h) << 17) + s * HDIM + d] = bfbits(val);
            }
        }
    }
}

// ---------------------------------------------------------------------------
// Kernel 2v: V projection, 512 blocks. OPERAND-SWAPPED MFMA so the
// [B,H,64,S] transposed store is s-contiguous per instruction.
// ---------------------------------------------------------------------------
__global__ __launch_bounds__(256) void v_gemm_kernel(
        const u16* __restrict__ Av, const u16* __restrict__ WT,
        const float* __restrict__ bias, u16* __restrict__ Vb,
        const int* __restrict__ cntp) {
    const int id  = blockIdx.x;
    const int r_  = id >> 3;
    const int grp = r_ >> 5, bnq = (r_ >> 2) & 7, bmin = r_ & 3;
    const int bm  = (id & 7) + 8 * (grp * 4 + bmin);
    const int bn  = bnq;

    const int cn = cntp[bm >> 4];
    if (((bm & 15) * 128) >= cn) return;

    __shared__ __align__(16) u16 As[2][128][32];
    __shared__ __align__(16) u16 Bs[2][128][32];

    const int tid  = threadIdx.x;
    const int lane = tid & 63, w = tid >> 6;
    const int g    = lane >> 4, l15 = lane & 15;
    const int wrow = w >> 1, wcol = w & 1;

    const char* pa[2]; const char* pb[2];
#pragma unroll
    for (int t = 0; t < 2; ++t) {
        const int rloc = w * 32 + t * 16 + (lane >> 2);
        const int scol = ((lane & 3) ^ ((lane >> 3) & 3)) * 8;
        pa[t] = (const char*)(Av + (size_t)(bm * 128 + rloc) * EDIM + scol);
        pb[t] = (const char*)(WT + (size_t)(bn * 128 + rloc) * EDIM + scol);
    }

    auto STAGE = [&](int bufn, int ko) {
        char* abase = (char*)&As[bufn][0][0] + w * 2048;
        char* bbase = (char*)&Bs[bufn][0][0] + w * 2048;
#pragma unroll
        for (int t = 0; t < 2; ++t) {
            glds16(pa[t] + (size_t)ko * 2, abase + t * 1024);
            glds16(pb[t] + (size_t)ko * 2, bbase + t * 1024);
        }
    };

    f32x4 acc[4][4] = {};
    constexpr int NT = EDIM / 32;

    STAGE(0, 0);
    __syncthreads();

    int buf = 0;
#pragma unroll 1
    for (int kt = 0; kt < NT; ++kt) {
        if (kt < NT - 1) STAGE(buf ^ 1, (kt + 1) * 32);

        bf16x8 af[4], bfr[4];
        const int x = (l15 >> 1) & 3;
#pragma unroll
        for (int i = 0; i < 4; ++i) {
            const int rowA = wrow * 64 + i * 16 + l15;
            af[i] = bc(*(const us8*)((const u16*)&As[buf][0][0] + rowA * 32 + ((g ^ x) * 8)));
            const int rowB = wcol * 64 + i * 16 + l15;
            bfr[i] = bc(*(const us8*)((const u16*)&Bs[buf][0][0] + rowB * 32 + ((g ^ x) * 8)));
        }

        // swapped operands: C rows <- W-side (n), cols <- A-side (m=s)
#pragma unroll
        for (int i = 0; i < 4; ++i)
#pragma unroll
            for (int j = 0; j < 4; ++j)
                acc[i][j] = __builtin_amdgcn_mfma_f32_16x16x32_bf16(bfr[j], af[i], acc[i][j], 0, 0, 0);

        __syncthreads();
        buf ^= 1;
    }

    // V epilogue (swapped): n = bn*128+wcol*64+j*16+g*4+r (row=d-dim),
    // m = bm*128+wrow*64+i*16+l15 (col=s) -> stores contiguous in s.
#pragma unroll
    for (int i = 0; i < 4; ++i) {
        const int mglob = bm * 128 + wrow * 64 + i * 16 + l15;
        const int bb = mglob >> 11, s = mglob & 2047;
        const bool dead = (s >= cn);
#pragma unroll
        for (int j = 0; j < 4; ++j) {
#pragma unroll
            for (int r = 0; r < 4; ++r) {
                const int gn = bn * 128 + wcol * 64 + j * 16 + g * 4 + r;
                float val = acc[i][j][r] + bias[gn];
                if (dead) val = 0.f;
                const int hh = gn >> 6, d = gn & 63;
                Vb[((size_t)(bb * NHEAD + hh) << 17) + (size_t)d * SEQ + s] = bfbits(val);
            }
        }
    }
}

// ---------------------------------------------------------------------------
// Kernel 2b: O-projection. C[M,N] fp32 = Abuf(bf16)[M,1024] * Wo + bo.
// ---------------------------------------------------------------------------
__global__ __launch_bounds__(256) void o_gemm_kernel(const u16* __restrict__ Ap,
                                                     const u16* __restrict__ WT,
                                                     const float* __restrict__ bias,
                                                     float* __restrict__ outp) {
    const int id  = blockIdx.x;
    const int r_  = id >> 3;
    const int grp = r_ >> 5, bnq = (r_ >> 2) & 7, bmin = r_ & 3;
    const int bm  = (id & 7) + 8 * (grp * 4 + bmin);
    const int bn  = bnq;

    __shared__ __align__(16) u16 As[2][128][32];
    __shared__ __align__(16) u16 Bs[2][128][32];

    const int tid  = threadIdx.x;
    const int lane = tid & 63, w = tid >> 6;
    const int g    = lane >> 4, l15 = lane & 15;
    const int wrow = w >> 1, wcol = w & 1;

    const char* pa[2]; const char* pb[2];
#pragma unroll
    for (int t = 0; t < 2; ++t) {
        const int rloc = w * 32 + t * 16 + (lane >> 2);
        const int scol = ((lane & 3) ^ ((lane >> 3) & 3)) * 8;
        pa[t] = (const char*)(Ap + (size_t)(bm * 128 + rloc) * EDIM + scol);
        pb[t] = (const char*)(WT + (size_t)(bn * 128 + rloc) * EDIM + scol);
    }

    auto STAGE = [&](int bufn, int ko) {
        char* abase = (char*)&As[bufn][0][0] + w * 2048;
        char* bbase = (char*)&Bs[bufn][0][0] + w * 2048;
#pragma unroll
        for (int t = 0; t < 2; ++t) {
            glds16(pa[t] + (size_t)ko * 2, abase + t * 1024);
            glds16(pb[t] + (size_t)ko * 2, bbase + t * 1024);
        }
    };

    f32x4 acc[4][4] = {};
    constexpr int NT = EDIM / 32;

    STAGE(0, 0);
    __syncthreads();

    int buf = 0;
#pragma unroll 1
    for (int kt = 0; kt < NT; ++kt) {
        if (kt < NT - 1) STAGE(buf ^ 1, (kt + 1) * 32);

        bf16x8 af[4], bfr[4];
        const int x = (l15 >> 1) & 3;
#pragma unroll
        for (int i = 0; i < 4; ++i) {
            const int rowA = wrow * 64 + i * 16 + l15;
            af[i] = bc(*(const us8*)((const u16*)&As[buf][0][0] + rowA * 32 + ((g ^ x) * 8)));
            const int rowB = wcol * 64 + i * 16 + l15;
            bfr[i] = bc(*(const us8*)((const u16*)&Bs[buf][0][0] + rowB * 32 + ((g ^ x) * 8)));
        }

#pragma unroll
        for (int i = 0; i < 4; ++i)
#pragma unroll
            for (int j = 0; j < 4; ++j)
                acc[i][j] = __builtin_amdgcn_mfma_f32_16x16x32_bf16(af[i], bfr[j], acc[i][j], 0, 0, 0);

        __syncthreads();
        buf ^= 1;
    }

#pragma unroll
    for (int i = 0; i < 4; ++i) {
#pragma unroll
        for (int j = 0; j < 4; ++j) {
            const int gm0 = bm * 128 + wrow * 64 + i * 16 + g * 4;
            const int gn  = bn * 128 + wcol * 64 + j * 16 + l15;
            const float bv = bias[gn];
#pragma unroll
            for (int r = 0; r < 4; ++r)
                outp[(size_t)(gm0 + r) * EDIM + gn] = acc[i][j][r] + bv;
        }
    }
}

// ---------------------------------------------------------------------------
// Kernel 3: flash attention over COMPACTED keys, 32x32 MFMA, in-register P.
// Swapped PV/rowsum (R15): O-stores 64B-contiguous, lane-local normalize.
// ---------------------------------------------------------------------------
__global__ __launch_bounds__(256) void attn_kernel(const u16* __restrict__ Q,
                                                   const u16* __restrict__ K,
                                                   const u16* __restrict__ VT,
                                                   const int* __restrict__ cntp,
                                                   u16* __restrict__ O) {
    __shared__ u16 Klds[2][64][64];
    __shared__ u16 Vlds[2][64][64];

    const int tid = threadIdx.x, lane = tid & 63, w = tid >> 6;
    const int h = lane >> 5, l31 = lane & 31;

    const int id  = blockIdx.x;             // 0..1023, XCD-aware mapping
    const int bh  = (id & 7) * 8 + ((id >> 3) >> 4);
    const int qb  = (id >> 3) & 15;
    const int b   = bh >> 4, hd_ = bh & 15;

    const u16* Qp = Q + ((size_t)bh << 17);
    const u16* Kp = K + ((size_t)bh << 17);
    const u16* Vp = VT + ((size_t)bh << 17);
    const int q0w = qb * 128 + w * 32;

    const int cn  = cntp[b];
    const int ktc = (cn + 63) >> 6;

    bf16x8 qf[4];
#pragma unroll
    for (int khd = 0; khd < 4; ++khd)
        qf[khd] = bc(*(const us8*)&Qp[(size_t)(q0w + l31) * HDIM + khd * 16 + h * 8]);

    const int b_  = l31 & 3, hp = (l31 >> 2) & 1, cc = l31 >> 3;
    const int piR = 16 * (cc & 1) + 8 * hp + 4 * (cc >> 1) + b_;
    const int swk = b_ | (hp << 2);
    const int swv = l31 & 7;

    const int lr = lane >> 3, lg = lane & 7;
    const u16* pKs[2]; const u16* pVs[2];
#pragma unroll
    for (int t = 0; t < 2; ++t) {
        const int rloc = w * 16 + t * 8 + lr;
        const int xk = (rloc & 3) | (((rloc >> 3) & 1) << 2);
        pKs[t] = Kp + (size_t)rloc * HDIM + ((lg ^ xk) << 3);
        const int xv = rloc & 7;
        pVs[t] = Vp + (size_t)rloc * SEQ + ((lg ^ xv) << 3);
    }

    auto STAGE = [&](int bufn, int kb) {
#pragma unroll
        for (int t = 0; t < 2; ++t) {
            glds16(pKs[t] + (size_t)kb * HDIM, &Klds[bufn][w * 16 + t * 8][0]);
            glds16(pVs[t] + kb,                &Vlds[bufn][w * 16 + t * 8][0]);
        }
    };

    f32x16 ot[2] = {};
    f32x16 ls = {};

    bf16x8 onesf;
#pragma unroll
    for (int j = 0; j < 8; ++j) onesf[j] = (__bf16)1.0f;

    STAGE(0, 0);
    __syncthreads();

    for (int kt = 0; kt < ktc; ++kt) {
        const int cur = kt & 1;
        const bool more = (kt + 1) < ktc;
        if (more) STAGE(cur ^ 1, (kt + 1) * 64);

        f32x16 st[2] = {};
        __builtin_amdgcn_s_setprio(1);
#pragma unroll
        for (int kb2 = 0; kb2 < 2; ++kb2) {
            const u16* Kr = &Klds[cur][kb2 * 32 + piR][0];
#pragma unroll
            for (int khd = 0; khd < 4; ++khd) {
                bf16x8 kf = bc(*(const us8*)&Kr[(khd * 16 + h * 8) ^ (swk << 3)]);
                st[kb2] = __builtin_amdgcn_mfma_f32_32x32x16_bf16(kf, qf[khd], st[kb2], 0, 0, 0);
            }
        }
        __builtin_amdgcn_s_setprio(0);

#pragma unroll
        for (int kb2 = 0; kb2 < 2; ++kb2)
#pragma unroll
            for (int e = 0; e < 16; ++e)
                st[kb2][e] = exp2fast(st[kb2][e]);

        if (kt == ktc - 1) {
            const int kbase = kt * 64;
#pragma unroll
            for (int kb2 = 0; kb2 < 2; ++kb2)
#pragma unroll
                for (int cp = 0; cp < 4; ++cp)
#pragma unroll
                    for (int j = 0; j < 4; ++j) {
                        const int key = kbase + kb2 * 32 + 16 * (cp & 1) + 4 * (cp >> 1) + 8 * h + j;
                        if (key >= cn) st[kb2][cp * 4 + j] = 0.f;
                    }
        }

        bf16x8 pf[4];
#pragma unroll
        for (int s = 0; s < 4; ++s) {
            const int kb2 = s >> 1, sel = (s & 1) * 4;
#pragma unroll
            for (int j = 0; j < 4; ++j) {
                pf[s][j]     = (__bf16)st[kb2][sel + j];
                pf[s][4 + j] = (__bf16)st[kb2][8 + sel + j];
            }
        }

        __builtin_amdgcn_s_setprio(1);
        // rowsum (swapped): ls rows = q = crow(e,h), all cols identical
#pragma unroll
        for (int s = 0; s < 4; ++s)
            ls = __builtin_amdgcn_mfma_f32_32x32x16_bf16(pf[s], onesf, ls, 0, 0, 0);
        // PV (swapped): A = P (rows q), B = V^T (cols d = l31)
#pragma unroll
        for (int dblk = 0; dblk < 2; ++dblk) {
            const u16* Vr = &Vlds[cur][dblk * 32 + l31][0];
#pragma unroll
            for (int s = 0; s < 4; ++s) {
                bf16x8 vf = bc(*(const us8*)&Vr[(s * 16 + h * 8) ^ (swv << 3)]);
                ot[dblk] = __builtin_amdgcn_mfma_f32_32x32x16_bf16(pf[s], vf, ot[dblk], 0, 0, 0);
            }
        }
        __builtin_amdgcn_s_setprio(0);

        __syncthreads();
    }

    // store: element e -> q = (e&3)+8*(e>>2)+4h, d = dblk*32 + l31
    const size_t rowbase = (size_t)b * SEQ + qb * 128 + w * 32;
#pragma unroll
    for (int e = 0; e < 16; ++e) {
        const int qrow = (e & 3) + 8 * (e >> 2) + 4 * h;
        const float iv = 1.f / ls[e];
        const size_t off = (rowbase + qrow) * EDIM + hd_ * HDIM;
        O[off + l31]      = bfbits(ot[0][e] * iv);
        O[off + 32 + l31] = bfbits(ot[1][e] * iv);
    }
}

// ---------------------------------------------------------------------------
extern "C" void kernel_launch(void* const* d_in, const int* in_sizes, int n_in,
                              void* d_out, int out_size, void* d_ws, size_t ws_size,
                              hipStream_t stream) {
    const float* query = (const float*)d_in[0];
    const float* key   = (const float*)d_in[1];
    const float* value = (const float*)d_in[2];
    const int*   mask  = (const int*)d_in[3];
    const float* Wq = (const float*)d_in[4];  const float* bq = (const float*)d_in[5];
    const float* Wk = (const float*)d_in[6];  const float* bk = (const float*)d_in[7];
    const float* Wv = (const float*)d_in[8];  const float* bv = (const float*)d_in[9];
    const float* Wo = (const float*)d_in[10]; const float* bo = (const float*)d_in[11];

    char* ws = (char*)d_ws;
    const size_t WT_BYTES  = (size_t)EDIM * EDIM * 2;      // 2 MiB
    const size_t BUF_BYTES = (size_t)MTOK * EDIM * 2;      // 16 MiB
    u16* wtq   = (u16*)(ws);                               // q,k,v,o contiguous
    u16* wtv   = (u16*)(ws + 2 * WT_BYTES);
    u16* wto   = (u16*)(ws + 3 * WT_BYTES);
    u16* Qbuf  = (u16*)(ws + 4 * WT_BYTES);
    u16* Kbuf  = (u16*)(ws + 4 * WT_BYTES + BUF_BYTES);
    u16* VTbuf = (u16*)(ws + 4 * WT_BYTES + 2 * BUF_BYTES);
    char* X    = ws + 4 * WT_BYTES + 3 * BUF_BYTES;
    u16* Qbf   = (u16*)X;
    u16* Kc    = (u16*)(X + BUF_BYTES);
    u16* Vc    = (u16*)(X + 2 * BUF_BYTES);
    u16* Abuf  = (u16*)X;          // overlays Qbf after projections consume it
    int* idxl  = (int*)(X + 3 * BUF_BYTES);
    int* cntp  = (int*)(X + 3 * BUF_BYTES + (size_t)MTOK * 4);

    prep_kernel<<<NBAT, 256, 0, stream>>>(mask, idxl, cntp);

    dim3 tgrid(32, 32, 4), tblk(32, 8);
    wtrans4_kernel<<<tgrid, tblk, 0, stream>>>(Wq, Wk, Wv, Wo, wtq);

    cvtg_kernel<<<2048, 256, 0, stream>>>(query, key, value,
                                          idxl, cntp, Qbf, Kc, Vc);

    qk_gemm_kernel<<<1024, 256, 0, stream>>>(Qbf, Kc, wtq, bq, bk,
                                             Qbuf, Kbuf, cntp);
    v_gemm_kernel<<<512, 256, 0, stream>>>(Vc, wtv, bv, VTbuf, cntp);

    attn_kernel<<<1024, 256, 0, stream>>>(Qbuf, Kbuf, VTbuf, cntp, Abuf);

    o_gemm_kernel<<<512, 256, 0, stream>>>(Abuf, wto, bo, (float*)d_out);
}

// Round 17
// 179.978 us; speedup vs baseline: 1.0800x; 1.0356x over previous
//
#include <hip/hip_runtime.h>

// MHA forward: out = softmax(mask(QK^T/8)) V, with QKV/out projections.
// B=4, S=2048, D=1024, H=16, hd=64. fp32 in/out, bf16 MFMA compute.
// Mask [B,1,1,S] -> compact K/V to unmasked keys (~50%). Softmax scale
// folded into K projection. Attn: LDS-staged K/V, conflict-free swizzles.
// (Revert to the round-9 configuration: best measured total, 179.7 us.)

#define SEQ   2048
#define EDIM  1024
#define NHEAD 16
#define HDIM  64
#define NBAT  4
#define MTOK  8192           // B*S

typedef __attribute__((ext_vector_type(8))) __bf16 bf16x8;
typedef __attribute__((ext_vector_type(4))) __bf16 bf16x4;
typedef __attribute__((ext_vector_type(4))) float f32x4;
typedef __attribute__((ext_vector_type(16))) float f32x16;
typedef __attribute__((ext_vector_type(8))) unsigned short us8;
typedef unsigned short u16;

// log2(e)/8 : folds the 1/sqrt(hd) scale and the exp->exp2 conversion
#define SCL   0.1803368801111244f

__device__ __forceinline__ u16 bfbits(float f) {
    __bf16 h = (__bf16)f;
    return __builtin_bit_cast(u16, h);
}
__device__ __forceinline__ bf16x8 bc(us8 v) { return __builtin_bit_cast(bf16x8, v); }
__device__ __forceinline__ float exp2fast(float x) {
    float r;
    asm("v_exp_f32 %0, %1" : "=v"(r) : "v"(x));
    return r;
}
// async global->LDS, 16B per lane; LDS dest = wave-uniform base + lane*16
__device__ __forceinline__ void glds16(const void* g, void* l) {
    __builtin_amdgcn_global_load_lds(
        (const __attribute__((address_space(1))) unsigned int*)g,
        (__attribute__((address_space(3))) unsigned int*)l, 16, 0, 0);
}

// ---------------------------------------------------------------------------
// Kernel 0: per-batch compaction of the key mask.
// ---------------------------------------------------------------------------
__global__ __launch_bounds__(256) void prep_kernel(const int* __restrict__ mask,
                                                   int* __restrict__ idxl,
                                                   int* __restrict__ cntp) {
    __shared__ int psum[257];
    const int b = blockIdx.x, t = threadIdx.x;
    const int* mp = mask + b * SEQ;
    int m8[8]; int s = 0;
#pragma unroll
    for (int i = 0; i < 8; ++i) { m8[i] = mp[t * 8 + i]; s += (m8[i] != 0); }
    psum[t + 1] = s;
    __syncthreads();
    if (t == 0) { psum[0] = 0; for (int i = 1; i <= 256; ++i) psum[i] += psum[i - 1]; }
    __syncthreads();
    int ex = psum[t];
#pragma unroll
    for (int i = 0; i < 8; ++i)
        if (m8[i] != 0) idxl[b * SEQ + (ex++)] = t * 8 + i;
    if (t == 0) cntp[b] = psum[256];
}

// ---------------------------------------------------------------------------
// Kernel 1: 4x W [K,N] fp32 -> WT [N,K] bf16 (transpose + cast)
// ---------------------------------------------------------------------------
__global__ __launch_bounds__(256) void wtrans4_kernel(const float* __restrict__ W0,
                                                      const float* __restrict__ W1,
                                                      const float* __restrict__ W2,
                                                      const float* __restrict__ W3,
                                                      u16* __restrict__ WT) {
    __shared__ float tile[32][33];
    const int tx = threadIdx.x, ty = threadIdx.y;
    const int bx = blockIdx.x,  by = blockIdx.y, wz = blockIdx.z;
    const float* W = (wz == 0) ? W0 : (wz == 1) ? W1 : (wz == 2) ? W2 : W3;
    u16* O = WT + (size_t)wz * EDIM * EDIM;
#pragma unroll
    for (int i = 0; i < 4; ++i)
        tile[ty + i * 8][tx] = W[(size_t)(by * 32 + ty + i * 8) * EDIM + bx * 32 + tx];
    __syncthreads();
#pragma unroll
    for (int i = 0; i < 4; ++i) {
        int n = bx * 32 + ty + i * 8;
        int k = by * 32 + tx;
        O[(size_t)n * EDIM + k] = bfbits(tile[tx][ty + i * 8]);
    }
}

// ---------------------------------------------------------------------------
// Kernel 2a: merged QKV projections, one 1536-block launch.
//   which = id>>9: 0=Q (no gather, [B,H,S,64]), 1=K (gather, scaled, same),
//                  2=V (gather, [B,H,64,S] transposed).
// fp32 A staged via glds16 (swizzled source cols), 2-buffer, 1 barrier/step.
// XCD-resident A-panel mapping on sub = id&511.
// ---------------------------------------------------------------------------
__global__ __launch_bounds__(256) void qkv_gemm_kernel(
        const float* __restrict__ Aq, const float* __restrict__ Ak,
        const float* __restrict__ Av, const u16* __restrict__ WTall,
        const float* __restrict__ bqp, const float* __restrict__ bkp,
        const float* __restrict__ bvp,
        u16* __restrict__ Qb, u16* __restrict__ Kb, u16* __restrict__ Vb,
        const int* __restrict__ idxl, const int* __restrict__ cntp) {
    const int id    = blockIdx.x;
    const int which = id >> 9;            // 0,1,2
    const int sub   = id & 511;
    const int r_    = sub >> 3;
    const int grp   = r_ >> 5, bnq = (r_ >> 2) & 7, bmin = r_ & 3;
    const int bm    = (sub & 7) + 8 * (grp * 4 + bmin);
    const int bn    = bnq;

    const float* A    = (which == 0) ? Aq : (which == 1) ? Ak : Av;
    const u16*   WT   = WTall + (size_t)which * EDIM * EDIM;
    const float* bias = (which == 0) ? bqp : (which == 1) ? bkp : bvp;
    u16*         outp = (which == 0) ? Qb : (which == 1) ? Kb : Vb;
    const float  oscale = (which == 1) ? SCL : 1.0f;
    const bool   gather = (which > 0);

    int cn = SEQ;
    if (gather) {
        cn = cntp[bm >> 4];
        if (((bm & 15) * 128) >= cn) return;
    }

    __shared__ __align__(16) float As[2][128 * 32];
    __shared__ __align__(16) u16   Bs[2][128][32];

    const int tid  = threadIdx.x;
    const int lane = tid & 63, w = tid >> 6;
    const int g    = lane >> 4, l15 = lane & 15;
    const int wrow = w >> 1, wcol = w & 1;

    const char* pa[4];
#pragma unroll
    for (int t = 0; t < 4; ++t) {
        const int rloc = w * 32 + t * 8 + (lane >> 3);
        int arow;
        if (gather) {
            const int sloc = (bm & 15) * 128 + rloc;
            const int gi = (sloc < cn) ? idxl[(bm >> 4) * SEQ + sloc] : 0;
            arow = (bm >> 4) * SEQ + gi;
        } else arow = bm * 128 + rloc;
        const int scol = ((lane & 7) ^ (lane >> 3)) * 4;     // fp32 slot xor
        pa[t] = (const char*)(A + (size_t)arow * EDIM + scol);
    }
    const char* pb[2];
#pragma unroll
    for (int t = 0; t < 2; ++t) {
        const int rloc = w * 32 + t * 16 + (lane >> 2);
        const int brow = bn * 128 + rloc;
        const int scol = ((lane & 3) ^ ((lane >> 3) & 3)) * 8;
        pb[t] = (const char*)(WT + (size_t)brow * EDIM + scol);
    }

    auto STAGE = [&](int bufn, int ko) {
        char* abase = (char*)&As[bufn][0] + w * 4096;
#pragma unroll
        for (int t = 0; t < 4; ++t)
            glds16(pa[t] + (size_t)ko * 4, abase + t * 1024);
        char* bbase = (char*)&Bs[bufn][0][0] + w * 2048;
#pragma unroll
        for (int t = 0; t < 2; ++t)
            glds16(pb[t] + (size_t)ko * 2, bbase + t * 1024);
    };

    f32x4 acc[4][4] = {};
    constexpr int NT = EDIM / 32;

    STAGE(0, 0);
    __syncthreads();

    int buf = 0;
#pragma unroll 1
    for (int kt = 0; kt < NT; ++kt) {
        if (kt < NT - 1) STAGE(buf ^ 1, (kt + 1) * 32);

        bf16x8 af[4], bfr[4];
        {
            const float* Ab = &As[buf][0];
            const int x = l15 & 7;
#pragma unroll
            for (int i = 0; i < 4; ++i) {
                const int row = wrow * 64 + i * 16 + l15;
                f32x4 u0 = *(const f32x4*)(Ab + row * 32 + (((2 * g)     ^ x) * 4));
                f32x4 u1 = *(const f32x4*)(Ab + row * 32 + (((2 * g + 1) ^ x) * 4));
#pragma unroll
                for (int j = 0; j < 4; ++j) {
                    af[i][j]     = (__bf16)u0[j];
                    af[i][4 + j] = (__bf16)u1[j];
                }
            }
        }
        {
            const int x = (l15 >> 1) & 3;
#pragma unroll
            for (int j = 0; j < 4; ++j) {
                const int row = wcol * 64 + j * 16 + l15;
                bfr[j] = bc(*(const us8*)((const u16*)&Bs[buf][0][0] + row * 32 + ((g ^ x) * 8)));
            }
        }

#pragma unroll
        for (int i = 0; i < 4; ++i)
#pragma unroll
            for (int j = 0; j < 4; ++j)
                acc[i][j] = __builtin_amdgcn_mfma_f32_16x16x32_bf16(af[i], bfr[j], acc[i][j], 0, 0, 0);

        __syncthreads();
        buf ^= 1;
    }

    // epilogue: C/D layout: col = lane&15, row = (lane>>4)*4 + r
#pragma unroll
    for (int i = 0; i < 4; ++i) {
#pragma unroll
        for (int j = 0; j < 4; ++j) {
            const int gm0 = bm * 128 + wrow * 64 + i * 16 + g * 4;
            const int gn  = bn * 128 + wcol * 64 + j * 16 + l15;
            const float bv = bias[gn];
#pragma unroll
            for (int r = 0; r < 4; ++r) {
                float val = (acc[i][j][r] + bv) * oscale;
                const int m = gm0 + r;
                if (gather && (m & 2047) >= cn) val = 0.f;
                const int b = m >> 11, s = m & 2047;
                const int h = gn >> 6, d = gn & 63;
                if (which == 2)
                    outp[((size_t)(b * NHEAD + h) << 17) + d * SEQ + s] = bfbits(val);
                else
                    outp[((size_t)(b * NHEAD + h) << 17) + s * HDIM + d] = bfbits(val);
            }
        }
    }
}

// ---------------------------------------------------------------------------
// Kernel 2b: O-projection. C[M,N] fp32 = Abuf(bf16)[M,1024] * Wo + bo.
// ---------------------------------------------------------------------------
__global__ __launch_bounds__(256) void o_gemm_kernel(const u16* __restrict__ Ap,
                                                     const u16* __restrict__ WT,
                                                     const float* __restrict__ bias,
                                                     float* __restrict__ outp) {
    const int id  = blockIdx.x;
    const int r_  = id >> 3;
    const int grp = r_ >> 5, bnq = (r_ >> 2) & 7, bmin = r_ & 3;
    const int bm  = (id & 7) + 8 * (grp * 4 + bmin);
    const int bn  = bnq;

    __shared__ __align__(16) u16 As[2][128][32];
    __shared__ __align__(16) u16 Bs[2][128][32];

    const int tid  = threadIdx.x;
    const int lane = tid & 63, w = tid >> 6;
    const int g    = lane >> 4, l15 = lane & 15;
    const int wrow = w >> 1, wcol = w & 1;

    const char* pa[2]; const char* pb[2];
#pragma unroll
    for (int t = 0; t < 2; ++t) {
        const int rloc = w * 32 + t * 16 + (lane >> 2);
        const int scol = ((lane & 3) ^ ((lane >> 3) & 3)) * 8;
        pa[t] = (const char*)(Ap + (size_t)(bm * 128 + rloc) * EDIM + scol);
        pb[t] = (const char*)(WT + (size_t)(bn * 128 + rloc) * EDIM + scol);
    }

    auto STAGE = [&](int bufn, int ko) {
        char* abase = (char*)&As[bufn][0][0] + w * 2048;
        char* bbase = (char*)&Bs[bufn][0][0] + w * 2048;
#pragma unroll
        for (int t = 0; t < 2; ++t) {
            glds16(pa[t] + (size_t)ko * 2, abase + t * 1024);
            glds16(pb[t] + (size_t)ko * 2, bbase + t * 1024);
        }
    };

    f32x4 acc[4][4] = {};
    constexpr int NT = EDIM / 32;

    STAGE(0, 0);
    __syncthreads();

    int buf = 0;
#pragma unroll 1
    for (int kt = 0; kt < NT; ++kt) {
        if (kt < NT - 1) STAGE(buf ^ 1, (kt + 1) * 32);

        bf16x8 af[4], bfr[4];
        const int x = (l15 >> 1) & 3;
#pragma unroll
        for (int i = 0; i < 4; ++i) {
            const int rowA = wrow * 64 + i * 16 + l15;
            af[i] = bc(*(const us8*)((const u16*)&As[buf][0][0] + rowA * 32 + ((g ^ x) * 8)));
            const int rowB = wcol * 64 + i * 16 + l15;
            bfr[i] = bc(*(const us8*)((const u16*)&Bs[buf][0][0] + rowB * 32 + ((g ^ x) * 8)));
        }

#pragma unroll
        for (int i = 0; i < 4; ++i)
#pragma unroll
            for (int j = 0; j < 4; ++j)
                acc[i][j] = __builtin_amdgcn_mfma_f32_16x16x32_bf16(af[i], bfr[j], acc[i][j], 0, 0, 0);

        __syncthreads();
        buf ^= 1;
    }

#pragma unroll
    for (int i = 0; i < 4; ++i) {
#pragma unroll
        for (int j = 0; j < 4; ++j) {
            const int gm0 = bm * 128 + wrow * 64 + i * 16 + g * 4;
            const int gn  = bn * 128 + wcol * 64 + j * 16 + l15;
            const float bv = bias[gn];
#pragma unroll
            for (int r = 0; r < 4; ++r)
                outp[(size_t)(gm0 + r) * EDIM + gn] = acc[i][j][r] + bv;
        }
    }
}

// ---------------------------------------------------------------------------
// Kernel 3: flash attention over COMPACTED keys, 32x32 MFMA, in-register P.
// 1D grid 1024 blocks (XCD-mapped), 256 threads = 4 waves x 32 q-rows.
// K pre-scaled by log2e/8 -> p = exp2(st); tail-pad keys zeroed last tile.
// Row-sum via ones-MFMA. K/V staged via glds16, 2-buffer, 1 barrier/tile.
// LDS swizzles (16B slots, involution sigma(r,s)=s^f(r)):
//   K: f(r) = (r&3) | (((r>>3)&1)<<2);  V: f(r) = r&7
// ---------------------------------------------------------------------------
__global__ __launch_bounds__(256) void attn_kernel(const u16* __restrict__ Q,
                                                   const u16* __restrict__ K,
                                                   const u16* __restrict__ VT,
                                                   const int* __restrict__ cntp,
                                                   u16* __restrict__ O) {
    __shared__ u16 Klds[2][64][64];
    __shared__ u16 Vlds[2][64][64];

    const int tid = threadIdx.x, lane = tid & 63, w = tid >> 6;
    const int h = lane >> 5, l31 = lane & 31;

    const int id  = blockIdx.x;             // 0..1023, XCD-aware mapping
    const int bh  = (id & 7) * 8 + ((id >> 3) >> 4);
    const int qb  = (id >> 3) & 15;
    const int b   = bh >> 4, hd_ = bh & 15;

    const u16* Qp = Q + ((size_t)bh << 17);
    const u16* Kp = K + ((size_t)bh << 17);
    const u16* Vp = VT + ((size_t)bh << 17);
    const int q0w = qb * 128 + w * 32;

    const int cn  = cntp[b];
    const int ktc = (cn + 63) >> 6;

    // Q fragments (B-operand): B[k=16*khd+8h+j][col=q=l31]
    bf16x8 qf[4];
#pragma unroll
    for (int khd = 0; khd < 4; ++khd)
        qf[khd] = bc(*(const us8*)&Qp[(size_t)(q0w + l31) * HDIM + khd * 16 + h * 8]);

    // key permutation (C-regs == PV B-fragments) + read-side swizzles
    const int b_  = l31 & 3, hp = (l31 >> 2) & 1, cc = l31 >> 3;
    const int piR = 16 * (cc & 1) + 8 * hp + 4 * (cc >> 1) + b_;
    const int swk = b_ | (hp << 2);
    const int swv = l31 & 7;

    // staging source pointers (glds: dest = wave base + lane*16, linear)
    const int lr = lane >> 3, lg = lane & 7;
    const u16* pKs[2]; const u16* pVs[2];
#pragma unroll
    for (int t = 0; t < 2; ++t) {
        const int rloc = w * 16 + t * 8 + lr;                 // LDS row 0..63
        const int xk = (rloc & 3) | (((rloc >> 3) & 1) << 2);
        pKs[t] = Kp + (size_t)rloc * HDIM + ((lg ^ xk) << 3);
        const int xv = rloc & 7;
        pVs[t] = Vp + (size_t)rloc * SEQ + ((lg ^ xv) << 3);
    }

    auto STAGE = [&](int bufn, int kb) {
#pragma unroll
        for (int t = 0; t < 2; ++t) {
            glds16(pKs[t] + (size_t)kb * HDIM, &Klds[bufn][w * 16 + t * 8][0]);
            glds16(pVs[t] + kb,                &Vlds[bufn][w * 16 + t * 8][0]);
        }
    };

    f32x16 ot[2] = {};
    f32x16 ls = {};

    bf16x8 onesf;
#pragma unroll
    for (int j = 0; j < 8; ++j) onesf[j] = (__bf16)1.0f;

    STAGE(0, 0);
    __syncthreads();

    for (int kt = 0; kt < ktc; ++kt) {
        const int cur = kt & 1;
        const bool more = (kt + 1) < ktc;
        if (more) STAGE(cur ^ 1, (kt + 1) * 64);

        f32x16 st[2] = {};
        __builtin_amdgcn_s_setprio(1);
#pragma unroll
        for (int kb2 = 0; kb2 < 2; ++kb2) {
            const u16* Kr = &Klds[cur][kb2 * 32 + piR][0];
#pragma unroll
            for (int khd = 0; khd < 4; ++khd) {
                bf16x8 kf = bc(*(const us8*)&Kr[(khd * 16 + h * 8) ^ (swk << 3)]);
                st[kb2] = __builtin_amdgcn_mfma_f32_32x32x16_bf16(kf, qf[khd], st[kb2], 0, 0, 0);
            }
        }
        __builtin_amdgcn_s_setprio(0);

#pragma unroll
        for (int kb2 = 0; kb2 < 2; ++kb2)
#pragma unroll
            for (int e = 0; e < 16; ++e)
                st[kb2][e] = exp2fast(st[kb2][e]);

        if (kt == ktc - 1) {
            const int kbase = kt * 64;
#pragma unroll
            for (int kb2 = 0; kb2 < 2; ++kb2)
#pragma unroll
                for (int cp = 0; cp < 4; ++cp)
#pragma unroll
                    for (int j = 0; j < 4; ++j) {
                        const int key = kbase + kb2 * 32 + 16 * (cp & 1) + 4 * (cp >> 1) + 8 * h + j;
                        if (key >= cn) st[kb2][cp * 4 + j] = 0.f;
                    }
        }

        bf16x8 pf[4];
#pragma unroll
        for (int s = 0; s < 4; ++s) {
            const int kb2 = s >> 1, sel = (s & 1) * 4;
#pragma unroll
            for (int j = 0; j < 4; ++j) {
                pf[s][j]     = (__bf16)st[kb2][sel + j];
                pf[s][4 + j] = (__bf16)st[kb2][8 + sel + j];
            }
        }

        __builtin_amdgcn_s_setprio(1);
#pragma unroll
        for (int s = 0; s < 4; ++s)
            ls = __builtin_amdgcn_mfma_f32_32x32x16_bf16(onesf, pf[s], ls, 0, 0, 0);
#pragma unroll
        for (int dblk = 0; dblk < 2; ++dblk) {
            const u16* Vr = &Vlds[cur][dblk * 32 + l31][0];
#pragma unroll
            for (int s = 0; s < 4; ++s) {
                bf16x8 vf = bc(*(const us8*)&Vr[(s * 16 + h * 8) ^ (swv << 3)]);
                ot[dblk] = __builtin_amdgcn_mfma_f32_32x32x16_bf16(vf, pf[s], ot[dblk], 0, 0, 0);
            }
        }
        __builtin_amdgcn_s_setprio(0);

        __syncthreads();
    }

    const float inv = 1.f / ls[0];

    // store: lane (h,l31) q=l31, d = dblk*32 + 8*cp + 4h + j
    const size_t row = (size_t)(b * SEQ + q0w + l31) * EDIM + hd_ * HDIM;
#pragma unroll
    for (int dblk = 0; dblk < 2; ++dblk) {
#pragma unroll
        for (int cp = 0; cp < 4; ++cp) {
            bf16x4 t;
#pragma unroll
            for (int j = 0; j < 4; ++j)
                t[j] = (__bf16)(ot[dblk][cp * 4 + j] * inv);
            *(bf16x4*)&O[row + dblk * 32 + 8 * cp + 4 * h] = t;
        }
    }
}

// ---------------------------------------------------------------------------
extern "C" void kernel_launch(void* const* d_in, const int* in_sizes, int n_in,
                              void* d_out, int out_size, void* d_ws, size_t ws_size,
                              hipStream_t stream) {
    const float* query = (const float*)d_in[0];
    const float* key   = (const float*)d_in[1];
    const float* value = (const float*)d_in[2];
    const int*   mask  = (const int*)d_in[3];
    const float* Wq = (const float*)d_in[4];  const float* bq = (const float*)d_in[5];
    const float* Wk = (const float*)d_in[6];  const float* bk = (const float*)d_in[7];
    const float* Wv = (const float*)d_in[8];  const float* bv = (const float*)d_in[9];
    const float* Wo = (const float*)d_in[10]; const float* bo = (const float*)d_in[11];

    char* ws = (char*)d_ws;
    const size_t WT_BYTES  = (size_t)EDIM * EDIM * 2;
    const size_t BUF_BYTES = (size_t)MTOK * EDIM * 2;
    u16* wtq   = (u16*)(ws);                    // q,k,v,o contiguous
    u16* wto   = (u16*)(ws + 3 * WT_BYTES);
    u16* Qbuf  = (u16*)(ws + 4 * WT_BYTES);
    u16* Kbuf  = (u16*)(ws + 4 * WT_BYTES + BUF_BYTES);
    u16* VTbuf = (u16*)(ws + 4 * WT_BYTES + 2 * BUF_BYTES);
    char* X    = ws + 4 * WT_BYTES + 3 * BUF_BYTES;
    u16* Abuf  = (u16*)X;
    int* idxl  = (int*)(X + BUF_BYTES);
    int* cntp  = (int*)(X + BUF_BYTES + (size_t)MTOK * 4);

    prep_kernel<<<NBAT, 256, 0, stream>>>(mask, idxl, cntp);

    dim3 tgrid(32, 32, 4), tblk(32, 8);
    wtrans4_kernel<<<tgrid, tblk, 0, stream>>>(Wq, Wk, Wv, Wo, wtq);

    qkv_gemm_kernel<<<1536, 256, 0, stream>>>(query, key, value, wtq,
                                              bq, bk, bv, Qbuf, Kbuf, VTbuf,
                                              idxl, cntp);

    attn_kernel<<<1024, 256, 0, stream>>>(Qbuf, Kbuf, VTbuf, cntp, Abuf);

    o_gemm_kernel<<<512, 256, 0, stream>>>(Abuf, wto, bo, (float*)d_out);
}